// Round 1
// baseline (1221.413 us; speedup 1.0000x reference)
//
#include <hip/hip_runtime.h>

// ---------------------------------------------------------------------------
// GATNet forward: 3x (GATConv -> ReLU -> BN) -> mean-pool -> MLP(128->64->1)
// N=100000, E=1.6M (+N self loops), HID=128, H=4, D=32, G=128, fp32 throughout.
// Strategy: build dst-CSR once (counting sort), then per layer:
//   k_gemm: h = x @ W[l]            (fp32 128x128 block tile, 8x8/thread)
//   k_attn: a_s/a_d per (node,head) dots
//   k_aggregate: one wave per dst node: softmax(max+sum passes) + weighted
//                gather of h[src] rows (2 floats/lane), fused bias+ReLU+BN.
// ---------------------------------------------------------------------------

__global__ void k_hist(const int* __restrict__ ei, int* __restrict__ deg,
                       int Ne, int Nn) {
    int e = blockIdx.x * 256 + threadIdx.x;
    if (e >= Ne + Nn) return;
    int d = (e < Ne) ? ei[Ne + e] : (e - Ne);
    atomicAdd(&deg[d], 1);
}

__global__ __launch_bounds__(512)
void k_scan_partial(const int* __restrict__ deg, int* __restrict__ tmp,
                    int* __restrict__ bsum, int Nn) {
    __shared__ int s0[512], s1[512];
    int t = threadIdx.x;
    int gi = blockIdx.x * 512 + t;
    int v = (gi < Nn) ? deg[gi] : 0;
    s0[t] = v;
    __syncthreads();
    int* src = s0; int* dst = s1;
    for (int off = 1; off < 512; off <<= 1) {
        int x = src[t];
        if (t >= off) x += src[t - off];
        dst[t] = x;
        __syncthreads();
        int* tw = src; src = dst; dst = tw;
    }
    if (gi < Nn) tmp[gi] = src[t];
    if (t == 511) bsum[blockIdx.x] = src[511];
}

__global__ __launch_bounds__(256)
void k_scan_bsums(int* bsum, int nb) {
    __shared__ int s0[256], s1[256];
    int t = threadIdx.x;
    int v = (t < nb) ? bsum[t] : 0;
    s0[t] = v;
    __syncthreads();
    int* src = s0; int* dst = s1;
    for (int off = 1; off < 256; off <<= 1) {
        int x = src[t];
        if (t >= off) x += src[t - off];
        dst[t] = x;
        __syncthreads();
        int* tw = src; src = dst; dst = tw;
    }
    if (t < nb) bsum[t] = src[t] - v;   // exclusive
}

__global__ void k_scan_add(const int* __restrict__ tmp, const int* __restrict__ bsum,
                           int* __restrict__ rowptr, int Nn) {
    int gi = blockIdx.x * 256 + threadIdx.x;
    if (gi < Nn) rowptr[gi + 1] = tmp[gi] + bsum[gi >> 9];
    if (gi == 0) rowptr[0] = 0;
}

__global__ void k_scatter(const int* __restrict__ ei, const int* __restrict__ rowptr,
                          int* __restrict__ cur, int* __restrict__ col,
                          int Ne, int Nn) {
    int e = blockIdx.x * 256 + threadIdx.x;
    if (e >= Ne + Nn) return;
    int s, d;
    if (e < Ne) { s = ei[e]; d = ei[Ne + e]; }
    else        { s = e - Ne; d = e - Ne; }
    int pos = rowptr[d] + atomicAdd(&cur[d], 1);
    col[pos] = s;
}

__global__ void k_bnprep(const float* __restrict__ gamma, const float* __restrict__ beta,
                         const float* __restrict__ mean, const float* __restrict__ var,
                         float* __restrict__ bn_mul, float* __restrict__ bn_add, int total) {
    int i = blockIdx.x * 256 + threadIdx.x;
    if (i >= total) return;
    float sc = gamma[i] / sqrtf(var[i] + 1e-5f);
    bn_mul[i] = sc;
    bn_add[i] = beta[i] - mean[i] * sc;
}

// fp32 GEMM: Hout[n][c] = sum_k X[n][k] * Wl[k][c];  M=Nn, K=128, Ncols=128
__global__ __launch_bounds__(256)
void k_gemm(const float* __restrict__ X, const float* __restrict__ Wl,
            float* __restrict__ Hout, int Nn) {
    __shared__ float As[16][132];   // [kk][row], +4 pad breaks write conflicts
    __shared__ float Bs[16][128];   // [kk][col]
    int t = threadIdx.x;
    int r0 = (t >> 4) << 3;         // 0..120
    int c0 = (t & 15) << 3;         // 0..120
    long rowBase = (long)blockIdx.x * 128;
    float acc[8][8];
#pragma unroll
    for (int i = 0; i < 8; ++i)
#pragma unroll
        for (int j = 0; j < 8; ++j) acc[i][j] = 0.f;

    for (int k0 = 0; k0 < 128; k0 += 16) {
#pragma unroll
        for (int i = 0; i < 2; ++i) {            // A tile: 128 rows x 16 k
            int q = t + (i << 8);                // 0..511
            int row = q >> 2;
            int kk4 = (q & 3) << 2;
            long gr = rowBase + row;
            float4 v = make_float4(0.f, 0.f, 0.f, 0.f);
            if (gr < Nn) v = *(const float4*)(X + gr * 128 + k0 + kk4);
            As[kk4 + 0][row] = v.x; As[kk4 + 1][row] = v.y;
            As[kk4 + 2][row] = v.z; As[kk4 + 3][row] = v.w;
        }
#pragma unroll
        for (int i = 0; i < 2; ++i) {            // B tile: 16 k x 128 cols
            int q = t + (i << 8);
            int kk = q >> 5;
            int cc = (q & 31) << 2;
            *(float4*)&Bs[kk][cc] = *(const float4*)(Wl + (k0 + kk) * 128 + cc);
        }
        __syncthreads();
#pragma unroll
        for (int kk = 0; kk < 16; ++kk) {
            float a[8], b[8];
            *(float4*)&a[0] = *(const float4*)&As[kk][r0];
            *(float4*)&a[4] = *(const float4*)&As[kk][r0 + 4];
            *(float4*)&b[0] = *(const float4*)&Bs[kk][c0];
            *(float4*)&b[4] = *(const float4*)&Bs[kk][c0 + 4];
#pragma unroll
            for (int i = 0; i < 8; ++i)
#pragma unroll
                for (int j = 0; j < 8; ++j)
                    acc[i][j] = fmaf(a[i], b[j], acc[i][j]);
        }
        __syncthreads();
    }
#pragma unroll
    for (int i = 0; i < 8; ++i) {
        long gr = rowBase + r0 + i;
        if (gr < Nn) {
            *(float4*)(Hout + gr * 128 + c0) =
                make_float4(acc[i][0], acc[i][1], acc[i][2], acc[i][3]);
            *(float4*)(Hout + gr * 128 + c0 + 4) =
                make_float4(acc[i][4], acc[i][5], acc[i][6], acc[i][7]);
        }
    }
}

// a_s[n,h] = sum_d h[n,h,d]*att_src[h,d];  a_d likewise. One thread per (n,h).
__global__ __launch_bounds__(256)
void k_attn(const float* __restrict__ Hb, const float* __restrict__ asrc,
            const float* __restrict__ adst, float* __restrict__ as_,
            float* __restrict__ ad_, int Nn) {
    __shared__ float sa[128], sd[128];
    int t = threadIdx.x;
    if (t < 128) sa[t] = asrc[t];
    else         sd[t - 128] = adst[t - 128];
    __syncthreads();
    int gid = blockIdx.x * 256 + t;
    if (gid >= Nn * 4) return;
    int n = gid >> 2, hh = gid & 3;
    const float* hp = Hb + (long)n * 128 + hh * 32;
    float s_ = 0.f, d_ = 0.f;
#pragma unroll
    for (int j = 0; j < 32; j += 4) {
        float4 hv = *(const float4*)(hp + j);
        const float* ap = sa + hh * 32 + j;
        const float* dp = sd + hh * 32 + j;
        s_ += hv.x * ap[0] + hv.y * ap[1] + hv.z * ap[2] + hv.w * ap[3];
        d_ += hv.x * dp[0] + hv.y * dp[1] + hv.z * dp[2] + hv.w * dp[3];
    }
    as_[gid] = s_;
    ad_[gid] = d_;
}

// One wave (64 lanes) per dst node. Phase A: per-head max & exp-sum over
// incoming edges (lane = edge_slot*4 + head, butterfly reduce). Phase B:
// serial edge loop, each lane owns 2 output cols; fused bias+ReLU+BN.
__global__ __launch_bounds__(256)
void k_aggregate(const float* __restrict__ Hb, const float* __restrict__ as_,
                 const float* __restrict__ ad_, const int* __restrict__ rowptr,
                 const int* __restrict__ col, const float* __restrict__ bias,
                 const float* __restrict__ bn_mul, const float* __restrict__ bn_add,
                 float* __restrict__ Xout, int Nn) {
    int n = (blockIdx.x << 2) + (threadIdx.x >> 6);
    if (n >= Nn) return;
    int lane = threadIdx.x & 63;
    int start = rowptr[n], end = rowptr[n + 1];

    int hh = lane & 3;
    float adn = ad_[n * 4 + hh];
    // pass 1: per-head max
    float m = -1e30f;
    for (int base = start; base < end; base += 16) {
        int idx = base + (lane >> 2);
        float sc = -1e30f;
        if (idx < end) {
            int s = col[idx];
            float e = as_[s * 4 + hh] + adn;
            sc = e > 0.f ? e : 0.2f * e;
        }
        m = fmaxf(m, sc);
    }
    for (int msk = 4; msk < 64; msk <<= 1) m = fmaxf(m, __shfl_xor(m, msk, 64));
    // pass 2: per-head sum of exp
    float den = 0.f;
    for (int base = start; base < end; base += 16) {
        int idx = base + (lane >> 2);
        if (idx < end) {
            int s = col[idx];
            float e = as_[s * 4 + hh] + adn;
            e = e > 0.f ? e : 0.2f * e;
            den += expf(e - m);
        }
    }
    for (int msk = 4; msk < 64; msk <<= 1) den += __shfl_xor(den, msk, 64);

    // redistribute (phase B: lane owns cols 2*lane, 2*lane+1 -> head = lane>>4)
    int hB = lane >> 4;
    float mB   = __shfl(m, hB, 64);
    float invB = 1.f / (__shfl(den, hB, 64) + 1e-16f);
    float adB  = ad_[n * 4 + hB];
    int c0 = lane << 1;
    float acc0 = 0.f, acc1 = 0.f;
    for (int i = start; i < end; ++i) {
        int s = col[i];
        float e = as_[s * 4 + hB] + adB;
        e = e > 0.f ? e : 0.2f * e;
        float alpha = expf(e - mB) * invB;
        float2 hv = *(const float2*)(Hb + (long)s * 128 + c0);
        acc0 = fmaf(hv.x, alpha, acc0);
        acc1 = fmaf(hv.y, alpha, acc1);
    }
    float v0 = acc0 + bias[c0], v1 = acc1 + bias[c0 + 1];
    v0 = fmaxf(v0, 0.f); v1 = fmaxf(v1, 0.f);
    v0 = fmaf(v0, bn_mul[c0], bn_add[c0]);
    v1 = fmaf(v1, bn_mul[c0 + 1], bn_add[c0 + 1]);
    *(float2*)(Xout + (long)n * 128 + c0) = make_float2(v0, v1);
}

// mean-pool: batch is sorted; block covers 64 nodes, thread = column,
// run-length accumulate in registers, one atomic per (graph-run, col).
__global__ __launch_bounds__(128)
void k_pool(const float* __restrict__ X, const int* __restrict__ batch,
            float* __restrict__ gsum, int* __restrict__ gcnt, int Nn) {
    int c = threadIdx.x;
    int n0 = blockIdx.x * 64;
    if (n0 >= Nn) return;
    int nend = (n0 + 64 < Nn) ? n0 + 64 : Nn;
    float local = 0.f;
    int gcur = batch[n0];
    int cnt = 0;
    for (int n = n0; n < nend; ++n) {
        int g = batch[n];
        if (g != gcur) {
            atomicAdd(&gsum[gcur * 128 + c], local);
            if (c == 0) atomicAdd(&gcnt[gcur], cnt);
            local = 0.f; cnt = 0; gcur = g;
        }
        local += X[(long)n * 128 + c];
        cnt += 1;
    }
    atomicAdd(&gsum[gcur * 128 + c], local);
    if (c == 0) atomicAdd(&gcnt[gcur], cnt);
}

// MLP head: one wave per graph. hdn[j]=relu(pooled.Wh1[:,j]+bh1[j]); reduce.
__global__ __launch_bounds__(64)
void k_head(const float* __restrict__ gsum, const int* __restrict__ gcnt,
            const float* __restrict__ Wh1, const float* __restrict__ bh1,
            const float* __restrict__ Wh2, const float* __restrict__ bh2,
            float* __restrict__ outp) {
    __shared__ float pooled[128];
    int g = blockIdx.x;
    int j = threadIdx.x;
    int cnt = gcnt[g];
    float inv = 1.f / (float)(cnt > 1 ? cnt : 1);
    pooled[j]      = gsum[g * 128 + j] * inv;
    pooled[j + 64] = gsum[g * 128 + 64 + j] * inv;
    __syncthreads();
    float acc = bh1[j];
    for (int k = 0; k < 128; ++k) acc = fmaf(pooled[k], Wh1[k * 64 + j], acc);
    acc = fmaxf(acc, 0.f);
    float prod = acc * Wh2[j];
    for (int msk = 1; msk < 64; msk <<= 1) prod += __shfl_xor(prod, msk, 64);
    if (j == 0) outp[g] = prod + bh2[0];
}

extern "C" void kernel_launch(void* const* d_in, const int* in_sizes, int n_in,
                              void* d_out, int out_size, void* d_ws, size_t ws_size,
                              hipStream_t stream) {
    const float* x       = (const float*)d_in[0];
    const int*   ei      = (const int*)d_in[1];
    const int*   batch   = (const int*)d_in[2];
    const float* W       = (const float*)d_in[3];
    const float* att_src = (const float*)d_in[4];
    const float* att_dst = (const float*)d_in[5];
    const float* bias    = (const float*)d_in[6];
    const float* gamma   = (const float*)d_in[7];
    const float* beta    = (const float*)d_in[8];
    const float* bn_mean = (const float*)d_in[9];
    const float* bn_var  = (const float*)d_in[10];
    const float* Wh1     = (const float*)d_in[11];
    const float* bh1     = (const float*)d_in[12];
    const float* Wh2     = (const float*)d_in[13];
    const float* bh2     = (const float*)d_in[14];
    float* out = (float*)d_out;

    const int Nn = in_sizes[0] / 128;
    const int Ne = in_sizes[1] / 2;
    const int Gg = out_size;
    const int nnz = Ne + Nn;

    char* ws = (char*)d_ws;
    size_t off = 0;
    auto alloc = [&](size_t bytes) -> char* {
        char* p = ws + off;
        off = (off + bytes + 255) & ~(size_t)255;
        return p;
    };
    float* bufA   = (float*)alloc((size_t)Nn * 128 * 4);
    float* bufB   = (float*)alloc((size_t)Nn * 128 * 4);
    float* as_    = (float*)alloc((size_t)Nn * 4 * 4);
    float* ad_    = (float*)alloc((size_t)Nn * 4 * 4);
    int*   rowptr = (int*)alloc((size_t)(Nn + 1) * 4);
    int*   cursor = (int*)alloc((size_t)Nn * 4);
    int*   col    = (int*)alloc((size_t)nnz * 4);   // also scan tmp
    int*   bsum   = (int*)alloc(1024);
    float* bn_mul = (float*)alloc(384 * 4);
    float* bn_add = (float*)alloc(384 * 4);
    float* gsum   = (float*)alloc((size_t)Gg * 128 * 4);
    int*   gcnt   = (int*)alloc((size_t)Gg * 4);

    // ---- CSR build (counting sort by dst, self-loops appended) ----
    hipMemsetAsync(cursor, 0, (size_t)Nn * 4, stream);
    k_hist<<<(nnz + 255) / 256, 256, 0, stream>>>(ei, cursor, Ne, Nn);
    int nb = (Nn + 511) / 512;
    k_scan_partial<<<nb, 512, 0, stream>>>(cursor, col, bsum, Nn);
    k_scan_bsums<<<1, 256, 0, stream>>>(bsum, nb);
    k_scan_add<<<(Nn + 255) / 256, 256, 0, stream>>>(col, bsum, rowptr, Nn);
    hipMemsetAsync(cursor, 0, (size_t)Nn * 4, stream);
    k_scatter<<<(nnz + 255) / 256, 256, 0, stream>>>(ei, rowptr, cursor, col, Ne, Nn);
    k_bnprep<<<2, 256, 0, stream>>>(gamma, beta, bn_mean, bn_var, bn_mul, bn_add, 384);

    // ---- 3 GAT layers ----
    const float* cur = x;
    for (int l = 0; l < 3; ++l) {
        k_gemm<<<(Nn + 127) / 128, 256, 0, stream>>>(cur, W + l * 128 * 128, bufB, Nn);
        k_attn<<<(Nn * 4 + 255) / 256, 256, 0, stream>>>(bufB, att_src + l * 128,
                                                         att_dst + l * 128, as_, ad_, Nn);
        k_aggregate<<<(Nn + 3) / 4, 256, 0, stream>>>(bufB, as_, ad_, rowptr, col,
                                                      bias + l * 128, bn_mul + l * 128,
                                                      bn_add + l * 128, bufA, Nn);
        cur = bufA;
    }

    // ---- pool + head ----
    hipMemsetAsync(gsum, 0, (size_t)Gg * 128 * 4, stream);
    hipMemsetAsync(gcnt, 0, (size_t)Gg * 4, stream);
    k_pool<<<(Nn + 63) / 64, 128, 0, stream>>>(bufA, batch, gsum, gcnt, Nn);
    k_head<<<Gg, 64, 0, stream>>>(gsum, gcnt, Wh1, bh1, Wh2, bh2, out);
}

// Round 2
// 916.126 us; speedup vs baseline: 1.3332x; 1.3332x over previous
//
#include <hip/hip_runtime.h>

// ---------------------------------------------------------------------------
// GATNet forward: 3x (GATConv -> ReLU -> BN) -> mean-pool -> MLP(128->64->1)
// N=100000, E=1.6M (+N self loops), HID=128, H=4, D=32, G=128, fp32 throughout.
// R1: k_aggregate restructured — one-shot per-wave softmax (lane=edge, alpha
// computed once per edge-head with __expf, stored in LDS), phase-B gathers
// 2 edges/iter at float4/lane. Fallback 3-pass path for deg>64 (P≈0).
// ---------------------------------------------------------------------------

__global__ void k_hist(const int* __restrict__ ei, int* __restrict__ deg,
                       int Ne, int Nn) {
    int e = blockIdx.x * 256 + threadIdx.x;
    if (e >= Ne + Nn) return;
    int d = (e < Ne) ? ei[Ne + e] : (e - Ne);
    atomicAdd(&deg[d], 1);
}

__global__ __launch_bounds__(512)
void k_scan_partial(const int* __restrict__ deg, int* __restrict__ tmp,
                    int* __restrict__ bsum, int Nn) {
    __shared__ int s0[512], s1[512];
    int t = threadIdx.x;
    int gi = blockIdx.x * 512 + t;
    int v = (gi < Nn) ? deg[gi] : 0;
    s0[t] = v;
    __syncthreads();
    int* src = s0; int* dst = s1;
    for (int off = 1; off < 512; off <<= 1) {
        int x = src[t];
        if (t >= off) x += src[t - off];
        dst[t] = x;
        __syncthreads();
        int* tw = src; src = dst; dst = tw;
    }
    if (gi < Nn) tmp[gi] = src[t];
    if (t == 511) bsum[blockIdx.x] = src[511];
}

__global__ __launch_bounds__(256)
void k_scan_bsums(int* bsum, int nb) {
    __shared__ int s0[256], s1[256];
    int t = threadIdx.x;
    int v = (t < nb) ? bsum[t] : 0;
    s0[t] = v;
    __syncthreads();
    int* src = s0; int* dst = s1;
    for (int off = 1; off < 256; off <<= 1) {
        int x = src[t];
        if (t >= off) x += src[t - off];
        dst[t] = x;
        __syncthreads();
        int* tw = src; src = dst; dst = tw;
    }
    if (t < nb) bsum[t] = src[t] - v;   // exclusive
}

__global__ void k_scan_add(const int* __restrict__ tmp, const int* __restrict__ bsum,
                           int* __restrict__ rowptr, int Nn) {
    int gi = blockIdx.x * 256 + threadIdx.x;
    if (gi < Nn) rowptr[gi + 1] = tmp[gi] + bsum[gi >> 9];
    if (gi == 0) rowptr[0] = 0;
}

__global__ void k_scatter(const int* __restrict__ ei, const int* __restrict__ rowptr,
                          int* __restrict__ cur, int* __restrict__ col,
                          int Ne, int Nn) {
    int e = blockIdx.x * 256 + threadIdx.x;
    if (e >= Ne + Nn) return;
    int s, d;
    if (e < Ne) { s = ei[e]; d = ei[Ne + e]; }
    else        { s = e - Ne; d = e - Ne; }
    int pos = rowptr[d] + atomicAdd(&cur[d], 1);
    col[pos] = s;
}

__global__ void k_bnprep(const float* __restrict__ gamma, const float* __restrict__ beta,
                         const float* __restrict__ mean, const float* __restrict__ var,
                         float* __restrict__ bn_mul, float* __restrict__ bn_add, int total) {
    int i = blockIdx.x * 256 + threadIdx.x;
    if (i >= total) return;
    float sc = gamma[i] / sqrtf(var[i] + 1e-5f);
    bn_mul[i] = sc;
    bn_add[i] = beta[i] - mean[i] * sc;
}

// fp32 GEMM: Hout[n][c] = sum_k X[n][k] * Wl[k][c];  M=Nn, K=128, Ncols=128
__global__ __launch_bounds__(256)
void k_gemm(const float* __restrict__ X, const float* __restrict__ Wl,
            float* __restrict__ Hout, int Nn) {
    __shared__ float As[16][132];
    __shared__ float Bs[16][128];
    int t = threadIdx.x;
    int r0 = (t >> 4) << 3;
    int c0 = (t & 15) << 3;
    long rowBase = (long)blockIdx.x * 128;
    float acc[8][8];
#pragma unroll
    for (int i = 0; i < 8; ++i)
#pragma unroll
        for (int j = 0; j < 8; ++j) acc[i][j] = 0.f;

    for (int k0 = 0; k0 < 128; k0 += 16) {
#pragma unroll
        for (int i = 0; i < 2; ++i) {
            int q = t + (i << 8);
            int row = q >> 2;
            int kk4 = (q & 3) << 2;
            long gr = rowBase + row;
            float4 v = make_float4(0.f, 0.f, 0.f, 0.f);
            if (gr < Nn) v = *(const float4*)(X + gr * 128 + k0 + kk4);
            As[kk4 + 0][row] = v.x; As[kk4 + 1][row] = v.y;
            As[kk4 + 2][row] = v.z; As[kk4 + 3][row] = v.w;
        }
#pragma unroll
        for (int i = 0; i < 2; ++i) {
            int q = t + (i << 8);
            int kk = q >> 5;
            int cc = (q & 31) << 2;
            *(float4*)&Bs[kk][cc] = *(const float4*)(Wl + (k0 + kk) * 128 + cc);
        }
        __syncthreads();
#pragma unroll
        for (int kk = 0; kk < 16; ++kk) {
            float a[8], b[8];
            *(float4*)&a[0] = *(const float4*)&As[kk][r0];
            *(float4*)&a[4] = *(const float4*)&As[kk][r0 + 4];
            *(float4*)&b[0] = *(const float4*)&Bs[kk][c0];
            *(float4*)&b[4] = *(const float4*)&Bs[kk][c0 + 4];
#pragma unroll
            for (int i = 0; i < 8; ++i)
#pragma unroll
                for (int j = 0; j < 8; ++j)
                    acc[i][j] = fmaf(a[i], b[j], acc[i][j]);
        }
        __syncthreads();
    }
#pragma unroll
    for (int i = 0; i < 8; ++i) {
        long gr = rowBase + r0 + i;
        if (gr < Nn) {
            *(float4*)(Hout + gr * 128 + c0) =
                make_float4(acc[i][0], acc[i][1], acc[i][2], acc[i][3]);
            *(float4*)(Hout + gr * 128 + c0 + 4) =
                make_float4(acc[i][4], acc[i][5], acc[i][6], acc[i][7]);
        }
    }
}

// a_s[n,h] = sum_d h[n,h,d]*att_src[h,d];  a_d likewise. One thread per (n,h).
__global__ __launch_bounds__(256)
void k_attn(const float* __restrict__ Hb, const float* __restrict__ asrc,
            const float* __restrict__ adst, float* __restrict__ as_,
            float* __restrict__ ad_, int Nn) {
    __shared__ float sa[128], sd[128];
    int t = threadIdx.x;
    if (t < 128) sa[t] = asrc[t];
    else         sd[t - 128] = adst[t - 128];
    __syncthreads();
    int gid = blockIdx.x * 256 + t;
    if (gid >= Nn * 4) return;
    int n = gid >> 2, hh = gid & 3;
    const float* hp = Hb + (long)n * 128 + hh * 32;
    float s_ = 0.f, d_ = 0.f;
#pragma unroll
    for (int j = 0; j < 32; j += 4) {
        float4 hv = *(const float4*)(hp + j);
        const float* ap = sa + hh * 32 + j;
        const float* dp = sd + hh * 32 + j;
        s_ += hv.x * ap[0] + hv.y * ap[1] + hv.z * ap[2] + hv.w * ap[3];
        d_ += hv.x * dp[0] + hv.y * dp[1] + hv.z * dp[2] + hv.w * dp[3];
    }
    as_[gid] = s_;
    ad_[gid] = d_;
}

#define LEAKY(x) ((x) > 0.f ? (x) : 0.2f * (x))

// One wave per dst node, 4 nodes per block.
// Fast path (deg<=64): lane=edge. One-shot softmax across lanes (float4 =
// 4 heads), alpha -> LDS. Phase B: 2 edges/iter, half-wave each, float4/lane.
__global__ __launch_bounds__(256)
void k_aggregate(const float* __restrict__ Hb, const float* __restrict__ as_,
                 const float* __restrict__ ad_, const int* __restrict__ rowptr,
                 const int* __restrict__ col, const float* __restrict__ bias,
                 const float* __restrict__ bn_mul, const float* __restrict__ bn_add,
                 float* __restrict__ Xout, int Nn) {
    __shared__ float s_alpha[4][64][4];
    __shared__ int   s_col[4][64];
    int w = threadIdx.x >> 6;
    int n = (blockIdx.x << 2) + w;
    if (n >= Nn) return;
    int lane = threadIdx.x & 63;
    int start = rowptr[n], end = rowptr[n + 1];
    int deg = end - start;

    if (deg <= 64) {
        // ---- one-shot softmax: lane owns edge `lane` (all 4 heads) ----
        int s = 0;
        float ex = -1e30f, ey = -1e30f, ez = -1e30f, ew = -1e30f;
        float4 ad4 = *(const float4*)(ad_ + 4 * n);
        if (lane < deg) {
            s = col[start + lane];
            float4 as4 = *(const float4*)(as_ + 4 * s);
            ex = LEAKY(as4.x + ad4.x);
            ey = LEAKY(as4.y + ad4.y);
            ez = LEAKY(as4.z + ad4.z);
            ew = LEAKY(as4.w + ad4.w);
        }
        float mx = ex, my = ey, mz = ez, mw = ew;
#pragma unroll
        for (int msk = 1; msk < 64; msk <<= 1) {
            mx = fmaxf(mx, __shfl_xor(mx, msk, 64));
            my = fmaxf(my, __shfl_xor(my, msk, 64));
            mz = fmaxf(mz, __shfl_xor(mz, msk, 64));
            mw = fmaxf(mw, __shfl_xor(mw, msk, 64));
        }
        float px = 0.f, py = 0.f, pz = 0.f, pw = 0.f;
        if (lane < deg) {
            px = __expf(ex - mx); py = __expf(ey - my);
            pz = __expf(ez - mz); pw = __expf(ew - mw);
        }
        float dx = px, dy = py, dz = pz, dw = pw;
#pragma unroll
        for (int msk = 1; msk < 64; msk <<= 1) {
            dx += __shfl_xor(dx, msk, 64);
            dy += __shfl_xor(dy, msk, 64);
            dz += __shfl_xor(dz, msk, 64);
            dw += __shfl_xor(dw, msk, 64);
        }
        s_alpha[w][lane][0] = px * (1.f / (dx + 1e-16f));
        s_alpha[w][lane][1] = py * (1.f / (dy + 1e-16f));
        s_alpha[w][lane][2] = pz * (1.f / (dz + 1e-16f));
        s_alpha[w][lane][3] = pw * (1.f / (dw + 1e-16f));
        s_col[w][lane] = s;

        // ---- phase B: 2 edges / iter, float4 per lane ----
        int half = lane >> 5;          // which edge of the pair
        int li   = lane & 31;          // cols 4*li .. 4*li+3
        int hB   = li >> 3;            // head of those cols
        float ac0 = 0.f, ac1 = 0.f, ac2 = 0.f, ac3 = 0.f;
        for (int j = 0; j < deg; j += 2) {
            int e = j + half;
            if (e < deg) {
                int sv = s_col[w][e];
                float a = s_alpha[w][e][hB];
                float4 hv = *(const float4*)(Hb + (long)sv * 128 + (li << 2));
                ac0 = fmaf(hv.x, a, ac0);
                ac1 = fmaf(hv.y, a, ac1);
                ac2 = fmaf(hv.z, a, ac2);
                ac3 = fmaf(hv.w, a, ac3);
            }
        }
        ac0 += __shfl_xor(ac0, 32, 64);
        ac1 += __shfl_xor(ac1, 32, 64);
        ac2 += __shfl_xor(ac2, 32, 64);
        ac3 += __shfl_xor(ac3, 32, 64);
        if (lane < 32) {
            int c0 = li << 2;
            float4 b4 = *(const float4*)(bias + c0);
            float4 m4 = *(const float4*)(bn_mul + c0);
            float4 a4 = *(const float4*)(bn_add + c0);
            float v0 = fmaxf(ac0 + b4.x, 0.f);
            float v1 = fmaxf(ac1 + b4.y, 0.f);
            float v2 = fmaxf(ac2 + b4.z, 0.f);
            float v3 = fmaxf(ac3 + b4.w, 0.f);
            v0 = fmaf(v0, m4.x, a4.x); v1 = fmaf(v1, m4.y, a4.y);
            v2 = fmaf(v2, m4.z, a4.z); v3 = fmaf(v3, m4.w, a4.w);
            *(float4*)(Xout + (long)n * 128 + c0) = make_float4(v0, v1, v2, v3);
        }
        return;
    }

    // ---- fallback (deg > 64): 3-pass, as R0 ----
    int hh = lane & 3;
    float adn = ad_[n * 4 + hh];
    float m = -1e30f;
    for (int base = start; base < end; base += 16) {
        int idx = base + (lane >> 2);
        float sc = -1e30f;
        if (idx < end) {
            int s = col[idx];
            float e = as_[s * 4 + hh] + adn;
            sc = LEAKY(e);
        }
        m = fmaxf(m, sc);
    }
    for (int msk = 4; msk < 64; msk <<= 1) m = fmaxf(m, __shfl_xor(m, msk, 64));
    float den = 0.f;
    for (int base = start; base < end; base += 16) {
        int idx = base + (lane >> 2);
        if (idx < end) {
            int s = col[idx];
            float e = as_[s * 4 + hh] + adn;
            e = LEAKY(e);
            den += __expf(e - m);
        }
    }
    for (int msk = 4; msk < 64; msk <<= 1) den += __shfl_xor(den, msk, 64);
    int hB = lane >> 4;
    float mB   = __shfl(m, hB, 64);
    float invB = 1.f / (__shfl(den, hB, 64) + 1e-16f);
    float adB  = ad_[n * 4 + hB];
    int c0 = lane << 1;
    float acc0 = 0.f, acc1 = 0.f;
    for (int i = start; i < end; ++i) {
        int s = col[i];
        float e = as_[s * 4 + hB] + adB;
        e = LEAKY(e);
        float alpha = __expf(e - mB) * invB;
        float2 hv = *(const float2*)(Hb + (long)s * 128 + c0);
        acc0 = fmaf(hv.x, alpha, acc0);
        acc1 = fmaf(hv.y, alpha, acc1);
    }
    float v0 = acc0 + bias[c0], v1 = acc1 + bias[c0 + 1];
    v0 = fmaxf(v0, 0.f); v1 = fmaxf(v1, 0.f);
    v0 = fmaf(v0, bn_mul[c0], bn_add[c0]);
    v1 = fmaf(v1, bn_mul[c0 + 1], bn_add[c0 + 1]);
    *(float2*)(Xout + (long)n * 128 + c0) = make_float2(v0, v1);
}

// mean-pool: batch sorted; block covers 64 nodes, thread = column.
__global__ __launch_bounds__(128)
void k_pool(const float* __restrict__ X, const int* __restrict__ batch,
            float* __restrict__ gsum, int* __restrict__ gcnt, int Nn) {
    int c = threadIdx.x;
    int n0 = blockIdx.x * 64;
    if (n0 >= Nn) return;
    int nend = (n0 + 64 < Nn) ? n0 + 64 : Nn;
    float local = 0.f;
    int gcur = batch[n0];
    int cnt = 0;
    for (int n = n0; n < nend; ++n) {
        int g = batch[n];
        if (g != gcur) {
            atomicAdd(&gsum[gcur * 128 + c], local);
            if (c == 0) atomicAdd(&gcnt[gcur], cnt);
            local = 0.f; cnt = 0; gcur = g;
        }
        local += X[(long)n * 128 + c];
        cnt += 1;
    }
    atomicAdd(&gsum[gcur * 128 + c], local);
    if (c == 0) atomicAdd(&gcnt[gcur], cnt);
}

__global__ __launch_bounds__(64)
void k_head(const float* __restrict__ gsum, const int* __restrict__ gcnt,
            const float* __restrict__ Wh1, const float* __restrict__ bh1,
            const float* __restrict__ Wh2, const float* __restrict__ bh2,
            float* __restrict__ outp) {
    __shared__ float pooled[128];
    int g = blockIdx.x;
    int j = threadIdx.x;
    int cnt = gcnt[g];
    float inv = 1.f / (float)(cnt > 1 ? cnt : 1);
    pooled[j]      = gsum[g * 128 + j] * inv;
    pooled[j + 64] = gsum[g * 128 + 64 + j] * inv;
    __syncthreads();
    float acc = bh1[j];
    for (int k = 0; k < 128; ++k) acc = fmaf(pooled[k], Wh1[k * 64 + j], acc);
    acc = fmaxf(acc, 0.f);
    float prod = acc * Wh2[j];
    for (int msk = 1; msk < 64; msk <<= 1) prod += __shfl_xor(prod, msk, 64);
    if (j == 0) outp[g] = prod + bh2[0];
}

extern "C" void kernel_launch(void* const* d_in, const int* in_sizes, int n_in,
                              void* d_out, int out_size, void* d_ws, size_t ws_size,
                              hipStream_t stream) {
    const float* x       = (const float*)d_in[0];
    const int*   ei      = (const int*)d_in[1];
    const int*   batch   = (const int*)d_in[2];
    const float* W       = (const float*)d_in[3];
    const float* att_src = (const float*)d_in[4];
    const float* att_dst = (const float*)d_in[5];
    const float* bias    = (const float*)d_in[6];
    const float* gamma   = (const float*)d_in[7];
    const float* beta    = (const float*)d_in[8];
    const float* bn_mean = (const float*)d_in[9];
    const float* bn_var  = (const float*)d_in[10];
    const float* Wh1     = (const float*)d_in[11];
    const float* bh1     = (const float*)d_in[12];
    const float* Wh2     = (const float*)d_in[13];
    const float* bh2     = (const float*)d_in[14];
    float* out = (float*)d_out;

    const int Nn = in_sizes[0] / 128;
    const int Ne = in_sizes[1] / 2;
    const int Gg = out_size;
    const int nnz = Ne + Nn;

    char* ws = (char*)d_ws;
    size_t off = 0;
    auto alloc = [&](size_t bytes) -> char* {
        char* p = ws + off;
        off = (off + bytes + 255) & ~(size_t)255;
        return p;
    };
    float* bufA   = (float*)alloc((size_t)Nn * 128 * 4);
    float* bufB   = (float*)alloc((size_t)Nn * 128 * 4);
    float* as_    = (float*)alloc((size_t)Nn * 4 * 4);
    float* ad_    = (float*)alloc((size_t)Nn * 4 * 4);
    int*   rowptr = (int*)alloc((size_t)(Nn + 1) * 4);
    int*   cursor = (int*)alloc((size_t)Nn * 4);
    int*   col    = (int*)alloc((size_t)nnz * 4);   // also scan tmp
    int*   bsum   = (int*)alloc(1024);
    float* bn_mul = (float*)alloc(384 * 4);
    float* bn_add = (float*)alloc(384 * 4);
    float* gsum   = (float*)alloc((size_t)Gg * 128 * 4);
    int*   gcnt   = (int*)alloc((size_t)Gg * 4);

    // ---- CSR build ----
    hipMemsetAsync(cursor, 0, (size_t)Nn * 4, stream);
    k_hist<<<(nnz + 255) / 256, 256, 0, stream>>>(ei, cursor, Ne, Nn);
    int nb = (Nn + 511) / 512;
    k_scan_partial<<<nb, 512, 0, stream>>>(cursor, col, bsum, Nn);
    k_scan_bsums<<<1, 256, 0, stream>>>(bsum, nb);
    k_scan_add<<<(Nn + 255) / 256, 256, 0, stream>>>(col, bsum, rowptr, Nn);
    hipMemsetAsync(cursor, 0, (size_t)Nn * 4, stream);
    k_scatter<<<(nnz + 255) / 256, 256, 0, stream>>>(ei, rowptr, cursor, col, Ne, Nn);
    k_bnprep<<<2, 256, 0, stream>>>(gamma, beta, bn_mean, bn_var, bn_mul, bn_add, 384);

    // ---- 3 GAT layers ----
    const float* cur = x;
    for (int l = 0; l < 3; ++l) {
        k_gemm<<<(Nn + 127) / 128, 256, 0, stream>>>(cur, W + l * 128 * 128, bufB, Nn);
        k_attn<<<(Nn * 4 + 255) / 256, 256, 0, stream>>>(bufB, att_src + l * 128,
                                                         att_dst + l * 128, as_, ad_, Nn);
        k_aggregate<<<(Nn + 3) / 4, 256, 0, stream>>>(bufB, as_, ad_, rowptr, col,
                                                      bias + l * 128, bn_mul + l * 128,
                                                      bn_add + l * 128, bufA, Nn);
        cur = bufA;
    }

    // ---- pool + head ----
    hipMemsetAsync(gsum, 0, (size_t)Gg * 128 * 4, stream);
    hipMemsetAsync(gcnt, 0, (size_t)Gg * 4, stream);
    k_pool<<<(Nn + 63) / 64, 128, 0, stream>>>(bufA, batch, gsum, gcnt, Nn);
    k_head<<<Gg, 64, 0, stream>>>(gsum, gcnt, Wh1, bh1, Wh2, bh2, out);
}